// Round 2
// baseline (566.639 us; speedup 1.0000x reference)
//
#include <hip/hip_runtime.h>

// Problem shape (fixed by reference setup_inputs): B=4, C=128, H=W=256, fp32.
constexpr int Bx = 4;
constexpr int Cx = 128;
constexpr int Hx = 256;
constexpr int Wx = 256;
constexpr int HWx = Hx * Wx;

// ---------------------------------------------------------------------------
// Kernel 1: per-(b,c) instance-norm statistics.
// One block per (b,c) group; 512 threads; float4 loads (16B/lane).
// stats[g] = mean, stats[B*C + g] = rsqrt(var + eps)
// ---------------------------------------------------------------------------
__global__ __launch_bounds__(512) void in_stats(const float* __restrict__ h,
                                                float* __restrict__ stats) {
    const int g = blockIdx.x;   // b*C + c
    const int t = threadIdx.x;
    const float4* p = reinterpret_cast<const float4*>(h + (size_t)g * HWx);

    float4 s4 = {0.f, 0.f, 0.f, 0.f};
    float4 q4 = {0.f, 0.f, 0.f, 0.f};
    for (int i = t; i < HWx / 4; i += 512) {
        float4 v = p[i];
        s4.x += v.x; s4.y += v.y; s4.z += v.z; s4.w += v.w;
        q4.x += v.x * v.x; q4.y += v.y * v.y;
        q4.z += v.z * v.z; q4.w += v.w * v.w;
    }
    float s = (s4.x + s4.y) + (s4.z + s4.w);
    float q = (q4.x + q4.y) + (q4.z + q4.w);

    // wave64 shuffle reduction, then cross-wave via LDS
    for (int off = 32; off > 0; off >>= 1) {
        s += __shfl_down(s, off, 64);
        q += __shfl_down(q, off, 64);
    }
    __shared__ float rs[8], rq[8];
    const int wid = t >> 6;
    if ((t & 63) == 0) { rs[wid] = s; rq[wid] = q; }
    __syncthreads();
    if (t == 0) {
        float S = 0.f, Q = 0.f;
        #pragma unroll
        for (int i = 0; i < 8; ++i) { S += rs[i]; Q += rq[i]; }
        const float mean = S * (1.0f / HWx);
        const float var  = Q * (1.0f / HWx) - mean * mean;
        stats[g]           = mean;
        stats[Bx * Cx + g] = rsqrtf(var + 1e-5f);
    }
}

// ---------------------------------------------------------------------------
// Kernel 2: fused bilinear-warp(gamma), bilinear-warp(beta), instance-norm
// apply, and combine. One thread per (b,y,x) pixel, looping all C channels:
// warp coords / weights / validity computed ONCE per 128 outputs.
// ---------------------------------------------------------------------------
__global__ __launch_bounds__(256) void fuse_kernel(
    const float* __restrict__ h,
    const float* __restrict__ gamma,
    const float* __restrict__ beta,
    const float* __restrict__ flow,
    const float* __restrict__ mask,
    const float* __restrict__ stats,
    float* __restrict__ out)
{
    const int p = blockIdx.x * 256 + threadIdx.x;  // 0 .. B*HW-1
    const int b   = p >> 16;         // / HW
    const int pix = p & (HWx - 1);
    const int y   = pix >> 8;
    const int x   = pix & (Wx - 1);

    const float fx = flow[(size_t)b * 2 * HWx + pix];
    const float fy = flow[(size_t)b * 2 * HWx + HWx + pix];
    const float m  = mask[(size_t)b * HWx + pix];

    // Replicate the reference arithmetic exactly (order + divisions):
    //   xs = x/(w-1); sx = 2*xs - 1 + 2*fx/w; ix = (sx+1)*0.5*(w-1)
    const float xs = (float)x / 255.0f;
    const float ys = (float)y / 255.0f;
    const float sx = 2.0f * xs - 1.0f + 2.0f * fx / 256.0f;
    const float sy = 2.0f * ys - 1.0f + 2.0f * fy / 256.0f;
    const float ix = (sx + 1.0f) * 0.5f * 255.0f;
    const float iy = (sy + 1.0f) * 0.5f * 255.0f;

    const float x0f = floorf(ix);
    const float y0f = floorf(iy);
    const float wx1 = ix - x0f;
    const float wy1 = iy - y0f;
    const int x0 = (int)x0f, y0 = (int)y0f;
    const int x1 = x0 + 1,  y1 = y0 + 1;

    const bool vx0 = (x0 >= 0) & (x0 <= Wx - 1);
    const bool vx1 = (x1 >= 0) & (x1 <= Wx - 1);
    const bool vy0 = (y0 >= 0) & (y0 <= Hx - 1);
    const bool vy1 = (y1 >= 0) & (y1 <= Hx - 1);
    const int cx0 = min(max(x0, 0), Wx - 1), cx1 = min(max(x1, 0), Wx - 1);
    const int cy0 = min(max(y0, 0), Hx - 1), cy1 = min(max(y1, 0), Hx - 1);

    const float w00 = (1.0f - wy1) * (1.0f - wx1) * ((vy0 & vx0) ? 1.f : 0.f);
    const float w01 = (1.0f - wy1) * wx1          * ((vy0 & vx1) ? 1.f : 0.f);
    const float w10 = wy1 * (1.0f - wx1)          * ((vy1 & vx0) ? 1.f : 0.f);
    const float w11 = wy1 * wx1                   * ((vy1 & vx1) ? 1.f : 0.f);

    const int o00 = cy0 * Wx + cx0, o01 = cy0 * Wx + cx1;
    const int o10 = cy1 * Wx + cx0, o11 = cy1 * Wx + cx1;

    const size_t bbase = (size_t)b * Cx * HWx;
    const float* __restrict__ gb = gamma + bbase;
    const float* __restrict__ bb = beta  + bbase;
    const float* __restrict__ hb = h     + bbase + pix;
    float* __restrict__       ob = out   + bbase + pix;
    const float* __restrict__ meanp = stats + b * Cx;
    const float* __restrict__ isp   = stats + Bx * Cx + b * Cx;

    #pragma unroll 8
    for (int c = 0; c < Cx; ++c) {
        const size_t coff = (size_t)c * HWx;
        const float gw = w00 * gb[coff + o00] + w01 * gb[coff + o01]
                       + w10 * gb[coff + o10] + w11 * gb[coff + o11];
        const float bw = w00 * bb[coff + o00] + w01 * bb[coff + o01]
                       + w10 * bb[coff + o10] + w11 * bb[coff + o11];
        const float hv = hb[coff];
        const float hn = (hv - meanp[c]) * isp[c];
        ob[coff] = (gw * m + hv * (1.0f - m)) * hn + bw;
    }
}

// ---------------------------------------------------------------------------
extern "C" void kernel_launch(void* const* d_in, const int* in_sizes, int n_in,
                              void* d_out, int out_size, void* d_ws, size_t ws_size,
                              hipStream_t stream) {
    const float* h     = (const float*)d_in[0];
    const float* gamma = (const float*)d_in[1];
    const float* beta  = (const float*)d_in[2];
    const float* flow  = (const float*)d_in[3];
    const float* mask  = (const float*)d_in[4];
    float* out   = (float*)d_out;
    float* stats = (float*)d_ws;   // 2 * B * C floats = 4 KiB

    in_stats<<<Bx * Cx, 512, 0, stream>>>(h, stats);
    fuse_kernel<<<(Bx * HWx) / 256, 256, 0, stream>>>(h, gamma, beta, flow, mask,
                                                      stats, out);
}

// Round 3
// 566.017 us; speedup vs baseline: 1.0011x; 1.0011x over previous
//
#include <hip/hip_runtime.h>

// Problem shape (fixed by reference setup_inputs): B=4, C=128, H=W=256, fp32.
constexpr int Bx = 4;
constexpr int Cx = 128;
constexpr int Hx = 256;
constexpr int Wx = 256;
constexpr int HWx = Hx * Wx;
constexpr int NCHUNK = 8;           // channel chunks (one per XCD via swizzle)
constexpr int CPT = Cx / NCHUNK;    // 16 channels per thread

// ---------------------------------------------------------------------------
// Kernel 1: per-(b,c) instance-norm statistics.
// One block per (b,c) group; 512 threads; float4 loads.
// stats interleaved: stats[2g] = mean, stats[2g+1] = rsqrt(var+eps)
// ---------------------------------------------------------------------------
__global__ __launch_bounds__(512) void in_stats(const float* __restrict__ h,
                                                float* __restrict__ stats) {
    const int g = blockIdx.x;   // b*C + c
    const int t = threadIdx.x;
    const float4* p = reinterpret_cast<const float4*>(h + (size_t)g * HWx);

    float4 s4 = {0.f, 0.f, 0.f, 0.f};
    float4 q4 = {0.f, 0.f, 0.f, 0.f};
    #pragma unroll 4
    for (int i = t; i < HWx / 4; i += 512) {
        float4 v = p[i];
        s4.x += v.x; s4.y += v.y; s4.z += v.z; s4.w += v.w;
        q4.x += v.x * v.x; q4.y += v.y * v.y;
        q4.z += v.z * v.z; q4.w += v.w * v.w;
    }
    float s = (s4.x + s4.y) + (s4.z + s4.w);
    float q = (q4.x + q4.y) + (q4.z + q4.w);

    for (int off = 32; off > 0; off >>= 1) {
        s += __shfl_down(s, off, 64);
        q += __shfl_down(q, off, 64);
    }
    __shared__ float rs[8], rq[8];
    const int wid = t >> 6;
    if ((t & 63) == 0) { rs[wid] = s; rq[wid] = q; }
    __syncthreads();
    if (t == 0) {
        float S = 0.f, Q = 0.f;
        #pragma unroll
        for (int i = 0; i < 8; ++i) { S += rs[i]; Q += rq[i]; }
        const float mean = S * (1.0f / HWx);
        const float var  = Q * (1.0f / HWx) - mean * mean;
        stats[2 * g]     = mean;
        stats[2 * g + 1] = rsqrtf(var + 1e-5f);
    }
}

// ---------------------------------------------------------------------------
// Kernel 2: fused warp(gamma), warp(beta), instance-norm apply, combine.
// One thread per (b,y,x) pixel x 16-channel chunk. Grid = 8192 blocks:
//   bid = chunk*1024 + b*256 + y   (after bijective XCD swizzle)
// so each XCD owns ONE channel chunk for all (b,y) -> vertical gather reuse
// (rows y±3) stays in that XCD's L2, and gamma/beta are HBM-fetched ~once.
// ---------------------------------------------------------------------------
__global__ __launch_bounds__(256) void fuse_kernel(
    const float* __restrict__ h,
    const float* __restrict__ gamma,
    const float* __restrict__ beta,
    const float* __restrict__ flow,
    const float* __restrict__ mask,
    const float* __restrict__ stats,
    float* __restrict__ out)
{
    constexpr int NWG = NCHUNK * Bx * Hx;            // 8192, %8 == 0
    const int orig = blockIdx.x;
    const int bid  = (orig & 7) * (NWG / 8) + (orig >> 3);  // bijective XCD swizzle

    const int chunk = bid >> 10;        // / (Bx*Hx)
    const int rem   = bid & 1023;
    const int b     = rem >> 8;
    const int y     = rem & (Hx - 1);
    const int x     = threadIdx.x;
    const int pix   = (y << 8) | x;

    const float fx = flow[(size_t)b * 2 * HWx + pix];
    const float fy = flow[(size_t)b * 2 * HWx + HWx + pix];
    const float m  = mask[(size_t)b * HWx + pix];

    // Replicate the reference arithmetic exactly (order + divisions):
    //   xs = x/(w-1); sx = 2*xs - 1 + 2*fx/w; ix = (sx+1)*0.5*(w-1)
    const float xs = (float)x / 255.0f;
    const float ys = (float)y / 255.0f;
    const float sx = 2.0f * xs - 1.0f + 2.0f * fx / 256.0f;
    const float sy = 2.0f * ys - 1.0f + 2.0f * fy / 256.0f;
    const float ix = (sx + 1.0f) * 0.5f * 255.0f;
    const float iy = (sy + 1.0f) * 0.5f * 255.0f;

    const float x0f = floorf(ix);
    const float y0f = floorf(iy);
    const float wx1 = ix - x0f;
    const float wy1 = iy - y0f;
    const int x0 = (int)x0f, y0 = (int)y0f;
    const int x1 = x0 + 1,  y1 = y0 + 1;

    const bool vx0 = (x0 >= 0) & (x0 <= Wx - 1);
    const bool vx1 = (x1 >= 0) & (x1 <= Wx - 1);
    const bool vy0 = (y0 >= 0) & (y0 <= Hx - 1);
    const bool vy1 = (y1 >= 0) & (y1 <= Hx - 1);
    const int cx0 = min(max(x0, 0), Wx - 1), cx1 = min(max(x1, 0), Wx - 1);
    const int cy0 = min(max(y0, 0), Hx - 1), cy1 = min(max(y1, 0), Hx - 1);

    const float w00 = (1.0f - wy1) * (1.0f - wx1) * ((vy0 & vx0) ? 1.f : 0.f);
    const float w01 = (1.0f - wy1) * wx1          * ((vy0 & vx1) ? 1.f : 0.f);
    const float w10 = wy1 * (1.0f - wx1)          * ((vy1 & vx0) ? 1.f : 0.f);
    const float w11 = wy1 * wx1                   * ((vy1 & vx1) ? 1.f : 0.f);

    const int o00 = cy0 * Wx + cx0, o01 = cy0 * Wx + cx1;
    const int o10 = cy1 * Wx + cx0, o11 = cy1 * Wx + cx1;

    const int c0 = chunk * CPT;
    const size_t cbase = (size_t)(b * Cx + c0) * HWx;
    const float* __restrict__ gb = gamma + cbase;
    const float* __restrict__ bb = beta  + cbase;
    const float* __restrict__ hb = h     + cbase + pix;
    float* __restrict__       ob = out   + cbase + pix;
    const float* __restrict__ stp = stats + 2 * (b * Cx + c0);

    #pragma unroll 4
    for (int c = 0; c < CPT; ++c) {
        const size_t coff = (size_t)c * HWx;
        const float gw = w00 * gb[coff + o00] + w01 * gb[coff + o01]
                       + w10 * gb[coff + o10] + w11 * gb[coff + o11];
        const float bw = w00 * bb[coff + o00] + w01 * bb[coff + o01]
                       + w10 * bb[coff + o10] + w11 * bb[coff + o11];
        const float hv = hb[coff];
        const float hn = (hv - stp[2 * c]) * stp[2 * c + 1];
        ob[coff] = (gw * m + hv * (1.0f - m)) * hn + bw;
    }
}

// ---------------------------------------------------------------------------
extern "C" void kernel_launch(void* const* d_in, const int* in_sizes, int n_in,
                              void* d_out, int out_size, void* d_ws, size_t ws_size,
                              hipStream_t stream) {
    const float* h     = (const float*)d_in[0];
    const float* gamma = (const float*)d_in[1];
    const float* beta  = (const float*)d_in[2];
    const float* flow  = (const float*)d_in[3];
    const float* mask  = (const float*)d_in[4];
    float* out   = (float*)d_out;
    float* stats = (float*)d_ws;   // 2 * B * C floats = 4 KiB

    in_stats<<<Bx * Cx, 512, 0, stream>>>(h, stats);
    fuse_kernel<<<NCHUNK * Bx * Hx, 256, 0, stream>>>(h, gamma, beta, flow, mask,
                                                      stats, out);
}

// Round 4
// 502.010 us; speedup vs baseline: 1.1287x; 1.1275x over previous
//
#include <hip/hip_runtime.h>

// Problem shape (fixed by reference setup_inputs): B=4, C=128, H=W=256, fp32.
constexpr int Bx = 4;
constexpr int Cx = 128;
constexpr int Hx = 256;
constexpr int Wx = 256;
constexpr int HWx = Hx * Wx;
constexpr int NCHUNK = 8;           // channel chunks (one per XCD via swizzle)
constexpr int CPT = Cx / NCHUNK;    // 16 channels per thread

// 8B load with only 4B alignment guaranteed. Best case: one global_load_dwordx2
// (gfx950 unaligned-access). Worst case: clang splits into 2 dwords (= old code).
struct f2u { float x, y; } __attribute__((packed, aligned(4)));
__device__ __forceinline__ f2u ld2u(const float* p) {
    return *reinterpret_cast<const f2u*>(p);
}

// ---------------------------------------------------------------------------
// Kernel 1: per-(b,c) instance-norm statistics.
// stats interleaved: stats[2g] = mean, stats[2g+1] = rsqrt(var+eps)
// ---------------------------------------------------------------------------
__global__ __launch_bounds__(512) void in_stats(const float* __restrict__ h,
                                                float* __restrict__ stats) {
    const int g = blockIdx.x;   // b*C + c
    const int t = threadIdx.x;
    const float4* p = reinterpret_cast<const float4*>(h + (size_t)g * HWx);

    float4 s4 = {0.f, 0.f, 0.f, 0.f};
    float4 q4 = {0.f, 0.f, 0.f, 0.f};
    #pragma unroll 4
    for (int i = t; i < HWx / 4; i += 512) {
        float4 v = p[i];
        s4.x += v.x; s4.y += v.y; s4.z += v.z; s4.w += v.w;
        q4.x += v.x * v.x; q4.y += v.y * v.y;
        q4.z += v.z * v.z; q4.w += v.w * v.w;
    }
    float s = (s4.x + s4.y) + (s4.z + s4.w);
    float q = (q4.x + q4.y) + (q4.z + q4.w);

    for (int off = 32; off > 0; off >>= 1) {
        s += __shfl_down(s, off, 64);
        q += __shfl_down(q, off, 64);
    }
    __shared__ float rs[8], rq[8];
    const int wid = t >> 6;
    if ((t & 63) == 0) { rs[wid] = s; rq[wid] = q; }
    __syncthreads();
    if (t == 0) {
        float S = 0.f, Q = 0.f;
        #pragma unroll
        for (int i = 0; i < 8; ++i) { S += rs[i]; Q += rq[i]; }
        const float mean = S * (1.0f / HWx);
        const float var  = Q * (1.0f / HWx) - mean * mean;
        stats[2 * g]     = mean;
        stats[2 * g + 1] = rsqrtf(var + 1e-5f);
    }
}

// ---------------------------------------------------------------------------
// Kernel 2: fused warp(gamma), warp(beta), instance-norm apply, combine.
// Gather-instruction-minimized: the two x-corners are fetched as ONE float2
// per source row (boundary-exact via clamp-to-W-2 base + select), so each
// channel-iter issues 4 scattered loads instead of 8. Theory: per-CU
// scattered-VMEM addressing at ~39 cyc/instr is the binding resource
// (duration invariant across occupancy 35->83% and FETCH 875->209MB).
// ---------------------------------------------------------------------------
__global__ __launch_bounds__(256) void fuse_kernel(
    const float* __restrict__ h,
    const float* __restrict__ gamma,
    const float* __restrict__ beta,
    const float* __restrict__ flow,
    const float* __restrict__ mask,
    const float* __restrict__ stats,
    float* __restrict__ out)
{
    constexpr int NWG = NCHUNK * Bx * Hx;            // 8192, %8 == 0
    const int orig = blockIdx.x;
    const int bid  = (orig & 7) * (NWG / 8) + (orig >> 3);  // bijective XCD swizzle

    const int chunk = bid >> 10;        // / (Bx*Hx)
    const int rem   = bid & 1023;
    const int b     = rem >> 8;
    const int y     = rem & (Hx - 1);
    const int x     = threadIdx.x;
    const int pix   = (y << 8) | x;

    const float fx = flow[(size_t)b * 2 * HWx + pix];
    const float fy = flow[(size_t)b * 2 * HWx + HWx + pix];
    const float m  = mask[(size_t)b * HWx + pix];

    // Replicate the reference arithmetic exactly (order + divisions):
    //   xs = x/(w-1); sx = 2*xs - 1 + 2*fx/w; ix = (sx+1)*0.5*(w-1)
    const float xs = (float)x / 255.0f;
    const float ys = (float)y / 255.0f;
    const float sx = 2.0f * xs - 1.0f + 2.0f * fx / 256.0f;
    const float sy = 2.0f * ys - 1.0f + 2.0f * fy / 256.0f;
    const float ix = (sx + 1.0f) * 0.5f * 255.0f;
    const float iy = (sy + 1.0f) * 0.5f * 255.0f;

    const float x0f = floorf(ix);
    const float y0f = floorf(iy);
    const float wx1 = ix - x0f;
    const float wy1 = iy - y0f;
    const int x0 = (int)x0f, y0 = (int)y0f;
    const int x1 = x0 + 1,  y1 = y0 + 1;

    const bool vx0 = (x0 >= 0) & (x0 <= Wx - 1);
    const bool vx1 = (x1 >= 0) & (x1 <= Wx - 1);
    const bool vy0 = (y0 >= 0) & (y0 <= Hx - 1);
    const bool vy1 = (y1 >= 0) & (y1 <= Hx - 1);
    const int cx0 = min(max(x0, 0), Wx - 1), cx1 = min(max(x1, 0), Wx - 1);
    const int cy0 = min(max(y0, 0), Hx - 1), cy1 = min(max(y1, 0), Hx - 1);

    const float w00 = (1.0f - wy1) * (1.0f - wx1) * ((vy0 & vx0) ? 1.f : 0.f);
    const float w01 = (1.0f - wy1) * wx1          * ((vy0 & vx1) ? 1.f : 0.f);
    const float w10 = wy1 * (1.0f - wx1)          * ((vy1 & vx0) ? 1.f : 0.f);
    const float w11 = wy1 * wx1                   * ((vy1 & vx1) ? 1.f : 0.f);

    // Paired-corner fetch: float2 at column cb covers {cb, cb+1} which always
    // contains {cx0, cx1}: interior -> (x0, x0+1); x0=255 -> both at .y;
    // x0=-1 -> both at .x; fully-OOB lanes have zero weights, values harmless.
    const int  cb   = min(max(x0, 0), Wx - 2);
    const bool sel0 = (cx0 == cb);
    const bool sel1 = (cx1 == cb);
    const int  oT   = cy0 * Wx + cb;   // top-row pair offset
    const int  oB   = cy1 * Wx + cb;   // bottom-row pair offset

    const int c0 = chunk * CPT;
    const size_t cbase = (size_t)(b * Cx + c0) * HWx;
    const float* __restrict__ gb = gamma + cbase;
    const float* __restrict__ bb = beta  + cbase;
    const float* __restrict__ hb = h     + cbase + pix;
    float* __restrict__       ob = out   + cbase + pix;
    const float* __restrict__ stp = stats + 2 * (b * Cx + c0);

    #pragma unroll 4
    for (int c = 0; c < CPT; ++c) {
        const size_t coff = (size_t)c * HWx;
        const f2u gT = ld2u(gb + coff + oT);
        const f2u gB = ld2u(gb + coff + oB);
        const f2u bT = ld2u(bb + coff + oT);
        const f2u bB = ld2u(bb + coff + oB);
        const float hv = hb[coff];

        const float g00 = sel0 ? gT.x : gT.y, g01 = sel1 ? gT.x : gT.y;
        const float g10 = sel0 ? gB.x : gB.y, g11 = sel1 ? gB.x : gB.y;
        const float b00 = sel0 ? bT.x : bT.y, b01 = sel1 ? bT.x : bT.y;
        const float b10 = sel0 ? bB.x : bB.y, b11 = sel1 ? bB.x : bB.y;

        const float gw = w00 * g00 + w01 * g01 + w10 * g10 + w11 * g11;
        const float bw = w00 * b00 + w01 * b01 + w10 * b10 + w11 * b11;
        const float hn = (hv - stp[2 * c]) * stp[2 * c + 1];
        ob[coff] = (gw * m + hv * (1.0f - m)) * hn + bw;
    }
}

// ---------------------------------------------------------------------------
extern "C" void kernel_launch(void* const* d_in, const int* in_sizes, int n_in,
                              void* d_out, int out_size, void* d_ws, size_t ws_size,
                              hipStream_t stream) {
    const float* h     = (const float*)d_in[0];
    const float* gamma = (const float*)d_in[1];
    const float* beta  = (const float*)d_in[2];
    const float* flow  = (const float*)d_in[3];
    const float* mask  = (const float*)d_in[4];
    float* out   = (float*)d_out;
    float* stats = (float*)d_ws;   // 2 * B * C floats = 4 KiB

    in_stats<<<Bx * Cx, 512, 0, stream>>>(h, stats);
    fuse_kernel<<<NCHUNK * Bx * Hx, 256, 0, stream>>>(h, gamma, beta, flow, mask,
                                                      stats, out);
}